// Round 1
// baseline (408.854 us; speedup 1.0000x reference)
//
#include <hip/hip_runtime.h>
#include <math.h>

// B=16, N=2048, F=64, T=32; x:(B,N,F,T) fp32 256MiB; out:(B,T,T) fp32.
// Factorization:
//   lhs1[b,t,f] = sum_n x[b,n,f,t]*U1[n]
//   rhs[b,n,t]  = sum_f U3[f]*x[b,n,f,t]
//   R2[b,f,s]   = sum_n U2[f,n]*rhs[b,n,s]
//   product[b,t,s] = sum_f lhs1[b,t,f]*R2[b,f,s]
//   E = V_e @ sigmoid(product + b_e);  softmax over axis 1 (u).

#define BDIM 16
#define NDIM 2048
#define FDIM 64
#define TDIM 32
#define GPB  32   // blocks per batch in k1

// ---------------- kernel 1: single pass over x ----------------
// grid = BDIM*GPB blocks, 256 threads (4 waves). Each wave handles
// n = (gb*4+wave) + k*(GPB*4). Per n: 8 float4 loads/lane covering the
// 64x32 slice; accumulate lhs1 partial in regs, rhs via shfl_xor reduce.
__global__ __launch_bounds__(256) void k1_pass(
    const float* __restrict__ x, const float* __restrict__ U1,
    const float* __restrict__ U3, float* __restrict__ rhs_ws,
    float* __restrict__ lhs_part) {
  const int b    = blockIdx.x / GPB;
  const int gb   = blockIdx.x % GPB;
  const int tid  = threadIdx.x;
  const int wave = tid >> 6;
  const int lane = tid & 63;
  const int frow = lane >> 3;        // 0..7
  const int t4   = (lane & 7) * 4;   // 0,4,...,28

  float u3v[8];
#pragma unroll
  for (int i = 0; i < 8; ++i) u3v[i] = U3[frow + 8 * i];

  float4 lacc[8];
#pragma unroll
  for (int i = 0; i < 8; ++i) lacc[i] = make_float4(0.f, 0.f, 0.f, 0.f);

  const int wb = gb * 4 + wave;  // 0..127
  for (int n = wb; n < NDIM; n += GPB * 4) {
    const float* base = x + ((size_t)(b * NDIM + n)) * (FDIM * TDIM);
    const float u1n = U1[n];
    float4 racc = make_float4(0.f, 0.f, 0.f, 0.f);
#pragma unroll
    for (int i = 0; i < 8; ++i) {
      const float4 v = *(const float4*)(base + (frow + 8 * i) * TDIM + t4);
      lacc[i].x = fmaf(u1n, v.x, lacc[i].x);
      lacc[i].y = fmaf(u1n, v.y, lacc[i].y);
      lacc[i].z = fmaf(u1n, v.z, lacc[i].z);
      lacc[i].w = fmaf(u1n, v.w, lacc[i].w);
      racc.x = fmaf(u3v[i], v.x, racc.x);
      racc.y = fmaf(u3v[i], v.y, racc.y);
      racc.z = fmaf(u3v[i], v.z, racc.z);
      racc.w = fmaf(u3v[i], v.w, racc.w);
    }
    // reduce racc over frow groups: lanes differing in bits 3,4,5
#pragma unroll
    for (int m = 8; m <= 32; m <<= 1) {
      racc.x += __shfl_xor(racc.x, m, 64);
      racc.y += __shfl_xor(racc.y, m, 64);
      racc.z += __shfl_xor(racc.z, m, 64);
      racc.w += __shfl_xor(racc.w, m, 64);
    }
    if (frow == 0) {
      *(float4*)(rhs_ws + ((size_t)(b * NDIM + n)) * TDIM + t4) = racc;
    }
  }

  // reduce lhs1 partials across the 4 waves via LDS, write block partial
  __shared__ float sred[4 * 2048];
  float* my = sred + wave * 2048;
#pragma unroll
  for (int i = 0; i < 8; ++i)
    *(float4*)(my + (frow + 8 * i) * TDIM + t4) = lacc[i];
  __syncthreads();
  float* outp = lhs_part + ((size_t)(b * GPB + gb)) * 2048;
  for (int p = tid; p < 2048; p += 256)
    outp[p] = sred[p] + sred[2048 + p] + sred[4096 + p] + sred[6144 + p];
}

// ---------------- kernel 2a: reduce lhs1 partials over GPB ----------------
__global__ __launch_bounds__(256) void k2a(const float* __restrict__ lhs_part,
                                           float* __restrict__ lhs1) {
  const int pos = blockIdx.x * 256 + threadIdx.x;  // 0..32767
  const int b = pos >> 11;
  const int p = pos & 2047;
  const float* src = lhs_part + (size_t)b * GPB * 2048 + p;
  float s = 0.f;
#pragma unroll
  for (int g = 0; g < GPB; ++g) s += src[g * 2048];
  lhs1[pos] = s;
}

// ---------------- kernel 2b: R2[b,f,s] = sum_n U2[f,n]*rhs[b,n,s] ----------
// grid = BDIM*8 blocks; block handles 8 f's. thread: (c=tid>>5 n-chunk, t=tid&31)
__global__ __launch_bounds__(256) void k2b(const float* __restrict__ rhs_ws,
                                           const float* __restrict__ U2,
                                           float* __restrict__ R2) {
  const int b  = blockIdx.x >> 3;
  const int fg = blockIdx.x & 7;
  const int tid = threadIdx.x;
  const int c = tid >> 5;
  const int t = tid & 31;
  float acc[8];
#pragma unroll
  for (int i = 0; i < 8; ++i) acc[i] = 0.f;
  const float* rbase = rhs_ws + (size_t)b * NDIM * TDIM;
  for (int i = 0; i < 256; ++i) {
    const int n = c * 256 + i;
    const float v = rbase[n * 32 + t];
#pragma unroll
    for (int fi = 0; fi < 8; ++fi)
      acc[fi] = fmaf(U2[(fg * 8 + fi) * NDIM + n], v, acc[fi]);
  }
  __shared__ float sred[8 * 8 * 32];  // [c][fi][t]
#pragma unroll
  for (int fi = 0; fi < 8; ++fi) sred[(c * 8 + fi) * 32 + t] = acc[fi];
  __syncthreads();
  const int fi = tid >> 5, tt = tid & 31;
  float s = 0.f;
#pragma unroll
  for (int cc = 0; cc < 8; ++cc) s += sred[(cc * 8 + fi) * 32 + tt];
  R2[(size_t)b * 2048 + (fg * 8 + fi) * 32 + tt] = s;
}

// ---------------- kernel 3: product, sigmoid, V_e, softmax ----------------
__global__ __launch_bounds__(1024) void k3(const float* __restrict__ lhs1,
                                           const float* __restrict__ R2,
                                           const float* __restrict__ b_e,
                                           const float* __restrict__ V_e,
                                           float* __restrict__ out) {
  const int b = blockIdx.x;
  const int tid = threadIdx.x;
  __shared__ float sl[2048], sr[2048], sS[1024], sE[1024], sVe[1024], sbe[1024];
  __shared__ float smax[32], ssum[32];
  for (int i = tid; i < 2048; i += 1024) {
    sl[i] = lhs1[b * 2048 + i];
    sr[i] = R2[b * 2048 + i];
  }
  if (tid < 1024) { sVe[tid] = V_e[tid]; sbe[tid] = b_e[tid]; }
  __syncthreads();
  const int t = tid >> 5, s = tid & 31;
  float p = 0.f;
#pragma unroll
  for (int f = 0; f < 64; ++f) p = fmaf(sl[f * 32 + t], sr[f * 32 + s], p);
  sS[t * 32 + s] = 1.f / (1.f + expf(-(p + sbe[t * 32 + s])));
  __syncthreads();
  float e = 0.f;
#pragma unroll
  for (int tt = 0; tt < 32; ++tt) e = fmaf(sVe[t * 32 + tt], sS[tt * 32 + s], e);
  sE[t * 32 + s] = e;  // t plays the role of u here
  __syncthreads();
  if (tid < 32) {
    float m = -1e30f;
    for (int uu = 0; uu < 32; ++uu) m = fmaxf(m, sE[uu * 32 + tid]);
    float sum = 0.f;
    for (int uu = 0; uu < 32; ++uu) sum += expf(sE[uu * 32 + tid] - m);
    smax[tid] = m;
    ssum[tid] = sum;
  }
  __syncthreads();
  out[b * 1024 + t * 32 + s] = expf(sE[t * 32 + s] - smax[s]) / ssum[s];
}

extern "C" void kernel_launch(void* const* d_in, const int* in_sizes, int n_in,
                              void* d_out, int out_size, void* d_ws, size_t ws_size,
                              hipStream_t stream) {
  const float* x   = (const float*)d_in[0];
  const float* U1  = (const float*)d_in[1];
  const float* U2  = (const float*)d_in[2];
  const float* U3  = (const float*)d_in[3];
  const float* b_e = (const float*)d_in[4];
  const float* V_e = (const float*)d_in[5];
  float* out = (float*)d_out;
  float* ws  = (float*)d_ws;

  // ws layout (floats): rhs 1,048,576 | lhs_part 1,048,576 | lhs1 32,768 | R2 32,768
  float* rhs_ws   = ws;
  float* lhs_part = ws + 1048576;
  float* lhs1     = ws + 2097152;
  float* R2       = ws + 2097152 + 32768;

  k1_pass<<<BDIM * GPB, 256, 0, stream>>>(x, U1, U3, rhs_ws, lhs_part);
  k2a<<<128, 256, 0, stream>>>(lhs_part, lhs1);
  k2b<<<BDIM * 8, 256, 0, stream>>>(rhs_ws, U2, R2);
  k3<<<BDIM, 1024, 0, stream>>>(lhs1, R2, b_e, V_e, out);
}